// Round 1
// baseline (520.485 us; speedup 1.0000x reference)
//
#include <hip/hip_runtime.h>

#define N_DRUG 50000
#define F_DRUG 256
#define E_DRUG 1000000
#define N_DIS  20000
#define F_DIS  128
#define E_DIS  640000
#define NHID   64

// out[i] = bias broadcast; covers both emb1 and emb2 regions.
__global__ void init_bias_kernel(float* __restrict__ out,
                                 const float* __restrict__ b1,
                                 const float* __restrict__ b2) {
    int idx = blockIdx.x * blockDim.x + threadIdx.x;
    const int n1 = N_DRUG * NHID;
    const int total = (N_DRUG + N_DIS) * NHID;
    if (idx < n1) {
        out[idx] = b1[idx & (NHID - 1)];
    } else if (idx < total) {
        out[idx] = b2[idx & (NHID - 1)];
    }
}

// h[M,64] = x[M,K] @ W[K,64]. One wave handles R rows; lane = output column.
// W[k][lane] is coalesced across lanes; x[row][k..k+3] is a wave-broadcast float4.
template <int K, int R>
__global__ void gemm_rows_kernel(const float* __restrict__ x,
                                 const float* __restrict__ W,
                                 float* __restrict__ h, int M) {
    int wave = (blockIdx.x * blockDim.x + threadIdx.x) >> 6;
    int lane = threadIdx.x & 63;
    int row0 = wave * R;
    if (row0 >= M) return;

    float acc[R];
#pragma unroll
    for (int r = 0; r < R; ++r) acc[r] = 0.f;

    if (row0 + R <= M) {
        for (int k = 0; k < K; k += 4) {
            float w0 = W[(k + 0) * NHID + lane];
            float w1 = W[(k + 1) * NHID + lane];
            float w2 = W[(k + 2) * NHID + lane];
            float w3 = W[(k + 3) * NHID + lane];
#pragma unroll
            for (int r = 0; r < R; ++r) {
                const float4 xv = *reinterpret_cast<const float4*>(
                    &x[(size_t)(row0 + r) * K + k]);
                acc[r] = fmaf(xv.x, w0, acc[r]);
                acc[r] = fmaf(xv.y, w1, acc[r]);
                acc[r] = fmaf(xv.z, w2, acc[r]);
                acc[r] = fmaf(xv.w, w3, acc[r]);
            }
        }
#pragma unroll
        for (int r = 0; r < R; ++r)
            h[(size_t)(row0 + r) * NHID + lane] = acc[r];
    } else {
        const int rem = M - row0;
        for (int k = 0; k < K; k += 4) {
            float w0 = W[(k + 0) * NHID + lane];
            float w1 = W[(k + 1) * NHID + lane];
            float w2 = W[(k + 2) * NHID + lane];
            float w3 = W[(k + 3) * NHID + lane];
            for (int r = 0; r < rem; ++r) {
                const float4 xv = *reinterpret_cast<const float4*>(
                    &x[(size_t)(row0 + r) * K + k]);
                acc[r] = fmaf(xv.x, w0, acc[r]);
                acc[r] = fmaf(xv.y, w1, acc[r]);
                acc[r] = fmaf(xv.z, w2, acc[r]);
                acc[r] = fmaf(xv.w, w3, acc[r]);
            }
        }
        for (int r = 0; r < rem; ++r)
            h[(size_t)(row0 + r) * NHID + lane] = acc[r];
    }
}

// One wave per edge: lane f adds h[src][f] into out[dst][f].
__global__ void scatter_edges_kernel(const int* __restrict__ ei,
                                     const float* __restrict__ h,
                                     float* __restrict__ out, int E) {
    long long idx = (long long)blockIdx.x * blockDim.x + threadIdx.x;
    int e = (int)(idx >> 6);
    int f = (int)(idx & 63);
    if (e >= E) return;
    int src = ei[e];
    int dst = ei[E + e];
    atomicAdd(&out[(size_t)dst * NHID + f], h[(size_t)src * NHID + f]);
}

extern "C" void kernel_launch(void* const* d_in, const int* in_sizes, int n_in,
                              void* d_out, int out_size, void* d_ws, size_t ws_size,
                              hipStream_t stream) {
    const float* drug_x = (const float*)d_in[0];
    const float* dis_x  = (const float*)d_in[1];
    const float* W1     = (const float*)d_in[2];
    const float* b1     = (const float*)d_in[3];
    const float* W2     = (const float*)d_in[4];
    const float* b2     = (const float*)d_in[5];
    const int*   ei1    = (const int*)d_in[6];
    const int*   ei2    = (const int*)d_in[7];
    float* out = (float*)d_out;

    float* h1 = (float*)d_ws;                       // N_DRUG*64 floats
    float* h2 = h1 + (size_t)N_DRUG * NHID;         // N_DIS*64 floats

    // 1) init output with biases
    {
        int total = (N_DRUG + N_DIS) * NHID;
        int blocks = (total + 255) / 256;
        init_bias_kernel<<<blocks, 256, 0, stream>>>(out, b1, b2);
    }
    // 2) dense GEMMs
    {
        int waves = (N_DRUG + 7) / 8;               // R=8
        int blocks = (waves * 64 + 255) / 256;
        gemm_rows_kernel<F_DRUG, 8><<<blocks, 256, 0, stream>>>(drug_x, W1, h1, N_DRUG);
    }
    {
        int waves = (N_DIS + 7) / 8;
        int blocks = (waves * 64 + 255) / 256;
        gemm_rows_kernel<F_DIS, 8><<<blocks, 256, 0, stream>>>(dis_x, W2, h2, N_DIS);
    }
    // 3) edge scatter-adds
    {
        long long threads = (long long)E_DRUG * 64;
        int blocks = (int)((threads + 255) / 256);
        scatter_edges_kernel<<<blocks, 256, 0, stream>>>(ei1, h1, out, E_DRUG);
    }
    {
        long long threads = (long long)E_DIS * 64;
        int blocks = (int)((threads + 255) / 256);
        scatter_edges_kernel<<<blocks, 256, 0, stream>>>(ei2, h2,
                                                         out + (size_t)N_DRUG * NHID, E_DIS);
    }
}

// Round 2
// 472.799 us; speedup vs baseline: 1.1009x; 1.1009x over previous
//
#include <hip/hip_runtime.h>

#define N_DRUG 50000
#define F_DRUG 256
#define E_DRUG 1000000
#define N_DIS  20000
#define F_DIS  128
#define E_DIS  640000
#define NHID   64

// ---------------- dense GEMM: h[M,64] = x[M,K] @ W[K,64] ----------------
// One wave handles R rows; lane = output column.
template <int K, int R>
__global__ void gemm_rows_kernel(const float* __restrict__ x,
                                 const float* __restrict__ W,
                                 float* __restrict__ h, int M) {
    int wave = (blockIdx.x * blockDim.x + threadIdx.x) >> 6;
    int lane = threadIdx.x & 63;
    int row0 = wave * R;
    if (row0 >= M) return;

    float acc[R];
#pragma unroll
    for (int r = 0; r < R; ++r) acc[r] = 0.f;

    if (row0 + R <= M) {
        for (int k = 0; k < K; k += 4) {
            float w0 = W[(k + 0) * NHID + lane];
            float w1 = W[(k + 1) * NHID + lane];
            float w2 = W[(k + 2) * NHID + lane];
            float w3 = W[(k + 3) * NHID + lane];
#pragma unroll
            for (int r = 0; r < R; ++r) {
                const float4 xv = *reinterpret_cast<const float4*>(
                    &x[(size_t)(row0 + r) * K + k]);
                acc[r] = fmaf(xv.x, w0, acc[r]);
                acc[r] = fmaf(xv.y, w1, acc[r]);
                acc[r] = fmaf(xv.z, w2, acc[r]);
                acc[r] = fmaf(xv.w, w3, acc[r]);
            }
        }
#pragma unroll
        for (int r = 0; r < R; ++r)
            h[(size_t)(row0 + r) * NHID + lane] = acc[r];
    } else {
        const int rem = M - row0;
        for (int k = 0; k < K; k += 4) {
            float w0 = W[(k + 0) * NHID + lane];
            float w1 = W[(k + 1) * NHID + lane];
            float w2 = W[(k + 2) * NHID + lane];
            float w3 = W[(k + 3) * NHID + lane];
            for (int r = 0; r < rem; ++r) {
                const float4 xv = *reinterpret_cast<const float4*>(
                    &x[(size_t)(row0 + r) * K + k]);
                acc[r] = fmaf(xv.x, w0, acc[r]);
                acc[r] = fmaf(xv.y, w1, acc[r]);
                acc[r] = fmaf(xv.z, w2, acc[r]);
                acc[r] = fmaf(xv.w, w3, acc[r]);
            }
        }
        for (int r = 0; r < rem; ++r)
            h[(size_t)(row0 + r) * NHID + lane] = acc[r];
    }
}

// ---------------- counting sort machinery ----------------
__global__ void zero2_kernel(int* __restrict__ a, int na, int* __restrict__ b, int nb) {
    int i = blockIdx.x * blockDim.x + threadIdx.x;
    if (i < na) a[i] = 0;
    else if (i < na + nb) b[i - na] = 0;
}

__global__ void hist_kernel(const int* __restrict__ ei, int* __restrict__ cnt, int E) {
    int i = blockIdx.x * blockDim.x + threadIdx.x;
    if (i < E) atomicAdd(&cnt[ei[E + i]], 1);
}

// Single kernel, 2 blocks: block 0 scans graph 1, block 1 scans graph 2.
// Exclusive scan of cnt[0..n) -> start[0..n], start[n] = total; cursor = copy of start.
__global__ void __launch_bounds__(1024)
exscan2_kernel(const int* __restrict__ cnt1, int* __restrict__ start1, int* __restrict__ cur1, int n1,
               const int* __restrict__ cnt2, int* __restrict__ start2, int* __restrict__ cur2, int n2) {
    const int* cnt; int* start; int* cur; int n;
    if (blockIdx.x == 0) { cnt = cnt1; start = start1; cur = cur1; n = n1; }
    else                 { cnt = cnt2; start = start2; cur = cur2; n = n2; }

    __shared__ int wsum[16];
    __shared__ int s_running;
    if (threadIdx.x == 0) s_running = 0;
    __syncthreads();

    int lane = threadIdx.x & 63;
    int wid  = threadIdx.x >> 6;

    for (int base = 0; base < n; base += 4096) {
        int e0 = base + threadIdx.x * 4;   // n is a multiple of 4, e0 is a multiple of 4
        int4 v = (e0 < n) ? *reinterpret_cast<const int4*>(&cnt[e0]) : make_int4(0, 0, 0, 0);
        int s0 = v.x;
        int s1 = s0 + v.y;
        int s2 = s1 + v.z;
        int s3 = s2 + v.w;
        int tsum = s3;
        // wave-inclusive scan of tsum
        int incl = tsum;
#pragma unroll
        for (int off = 1; off < 64; off <<= 1) {
            int t = __shfl_up(incl, off);
            if (lane >= off) incl += t;
        }
        if (lane == 63) wsum[wid] = incl;
        __syncthreads();
        int wave_excl = 0;
        for (int w = 0; w < wid; ++w) wave_excl += wsum[w];
        int excl_t = wave_excl + (incl - tsum) + s_running;
        if (e0 < n) {
            int4 o = make_int4(excl_t, excl_t + s0, excl_t + s1, excl_t + s2);
            *reinterpret_cast<int4*>(&start[e0]) = o;
            *reinterpret_cast<int4*>(&cur[e0])   = o;
        }
        __syncthreads();
        if (threadIdx.x == 1023) s_running += wave_excl + incl;
        __syncthreads();
    }
    if (threadIdx.x == 0) start[n] = s_running;
}

__global__ void place_kernel(const int* __restrict__ ei, int* __restrict__ cursor,
                             int* __restrict__ sorted_src, int E) {
    int i = blockIdx.x * blockDim.x + threadIdx.x;
    if (i < E) {
        int dst = ei[E + i];
        int pos = atomicAdd(&cursor[dst], 1);
        sorted_src[pos] = ei[i];
    }
}

// ---------------- segmented gather-reduce ----------------
// One wave per node; lane = feature. Edge ids loaded 64-at-a-time, broadcast via shfl.
__global__ void gather_reduce_kernel(const int* __restrict__ start,
                                     const int* __restrict__ sorted_src,
                                     const float* __restrict__ h,
                                     const float* __restrict__ bias,
                                     float* __restrict__ out, int N) {
    int wave = (blockIdx.x * blockDim.x + threadIdx.x) >> 6;
    int lane = threadIdx.x & 63;
    if (wave >= N) return;
    int s = start[wave];
    int e = start[wave + 1];
    float acc = bias[lane];
    for (int b = s; b < e; b += 64) {
        int m = e - b;
        if (m > 64) m = 64;
        int id = (lane < m) ? sorted_src[b + lane] : 0;
        for (int j = 0; j < m; ++j) {
            int srcn = __shfl(id, j);
            acc += h[(size_t)srcn * NHID + lane];
        }
    }
    out[(size_t)wave * NHID + lane] = acc;
}

extern "C" void kernel_launch(void* const* d_in, const int* in_sizes, int n_in,
                              void* d_out, int out_size, void* d_ws, size_t ws_size,
                              hipStream_t stream) {
    const float* drug_x = (const float*)d_in[0];
    const float* dis_x  = (const float*)d_in[1];
    const float* W1     = (const float*)d_in[2];
    const float* b1     = (const float*)d_in[3];
    const float* W2     = (const float*)d_in[4];
    const float* b2     = (const float*)d_in[5];
    const int*   ei1    = (const int*)d_in[6];
    const int*   ei2    = (const int*)d_in[7];
    float* out = (float*)d_out;

    // workspace layout (16B-aligned chunks)
    char* p = (char*)d_ws;
    float* h1 = (float*)p;            p += (size_t)N_DRUG * NHID * 4;
    float* h2 = (float*)p;            p += (size_t)N_DIS  * NHID * 4;
    int* cnt1   = (int*)p;            p += (size_t)N_DRUG * 4;
    int* start1 = (int*)p;            p += ((size_t)N_DRUG + 4) * 4;
    int* cur1   = (int*)p;            p += (size_t)N_DRUG * 4;
    int* cnt2   = (int*)p;            p += (size_t)N_DIS * 4;
    int* start2 = (int*)p;            p += ((size_t)N_DIS + 4) * 4;
    int* cur2   = (int*)p;            p += (size_t)N_DIS * 4;
    int* srt1   = (int*)p;            p += (size_t)E_DRUG * 4;
    int* srt2   = (int*)p;            /* p += E_DIS*4 */

    // 1) zero histograms
    {
        int total = N_DRUG + N_DIS;
        zero2_kernel<<<(total + 255) / 256, 256, 0, stream>>>(cnt1, N_DRUG, cnt2, N_DIS);
    }
    // 2) histograms of dst
    hist_kernel<<<(E_DRUG + 255) / 256, 256, 0, stream>>>(ei1, cnt1, E_DRUG);
    hist_kernel<<<(E_DIS  + 255) / 256, 256, 0, stream>>>(ei2, cnt2, E_DIS);
    // 3) exclusive scans (both graphs, one kernel)
    exscan2_kernel<<<2, 1024, 0, stream>>>(cnt1, start1, cur1, N_DRUG,
                                           cnt2, start2, cur2, N_DIS);
    // 4) place src ids in dst-sorted order
    place_kernel<<<(E_DRUG + 255) / 256, 256, 0, stream>>>(ei1, cur1, srt1, E_DRUG);
    place_kernel<<<(E_DIS  + 255) / 256, 256, 0, stream>>>(ei2, cur2, srt2, E_DIS);
    // 5) dense GEMMs
    {
        int waves = (N_DRUG + 7) / 8;
        int blocks = (waves * 64 + 255) / 256;
        gemm_rows_kernel<F_DRUG, 8><<<blocks, 256, 0, stream>>>(drug_x, W1, h1, N_DRUG);
    }
    {
        int waves = (N_DIS + 7) / 8;
        int blocks = (waves * 64 + 255) / 256;
        gemm_rows_kernel<F_DIS, 8><<<blocks, 256, 0, stream>>>(dis_x, W2, h2, N_DIS);
    }
    // 6) segmented gather-reduce (+bias, writes every output exactly once)
    gather_reduce_kernel<<<N_DRUG / 4, 256, 0, stream>>>(start1, srt1, h1, b1, out, N_DRUG);
    gather_reduce_kernel<<<N_DIS / 4, 256, 0, stream>>>(start2, srt2, h2, b2,
                                                        out + (size_t)N_DRUG * NHID, N_DIS);
}

// Round 3
// 283.922 us; speedup vs baseline: 1.8332x; 1.6652x over previous
//
#include <hip/hip_runtime.h>

#define N_DRUG 50000
#define F_DRUG 256
#define E_DRUG 1000000
#define N_DIS  20000
#define F_DIS  128
#define E_DIS  640000
#define NHID   64

typedef __bf16 bf16x8 __attribute__((ext_vector_type(8)));
typedef float  f32x4  __attribute__((ext_vector_type(4)));

// ---------------- prepack W -> bf16, MFMA-B-fragment layout ----------------
// Wp[((k>>3)*64 + col)*8 + (k&7)] = bf16(W[k*NHID + col])
__global__ void prepack_kernel(const float* __restrict__ W1, __bf16* __restrict__ Wp1, int n1,
                               const float* __restrict__ W2, __bf16* __restrict__ Wp2, int n2) {
    int i = blockIdx.x * blockDim.x + threadIdx.x;
    const float* W; __bf16* Wp; int idx;
    if (i < n1) { W = W1; Wp = Wp1; idx = i; }
    else if (i < n1 + n2) { W = W2; Wp = Wp2; idx = i - n1; }
    else return;
    int k = idx >> 6, col = idx & 63;
    Wp[((size_t)(k >> 3) * 64 + col) * 8 + (k & 7)] = (__bf16)W[idx];
}

// ---------------- MFMA GEMM: h[M,64] = bf16(x[M,K]) @ bf16(W[K,64]) ----------------
// block = 256 threads = 4 waves; wave computes 32 rows x 64 cols (M_REP=2).
template <int K>
__global__ void __launch_bounds__(256)
mfma_gemm_kernel(const float* __restrict__ x, const __bf16* __restrict__ Wp,
                 float* __restrict__ h, int M) {
    __shared__ __bf16 Wlds[K * 64];
    {
        const int4* src = (const int4*)Wp;
        int4* dst = (int4*)Wlds;
        const int nchunk = K * 64 * 2 / 16;  // K*8 int4 chunks
        for (int i = threadIdx.x; i < nchunk; i += 256) dst[i] = src[i];
    }
    __syncthreads();

    const int wid = threadIdx.x >> 6, lane = threadIdx.x & 63;
    const int l15 = lane & 15, lhi = lane >> 4;
    const int r0 = blockIdx.x * 128 + wid * 32;
    if (r0 >= M) return;

    f32x4 acc[2][4];
#pragma unroll
    for (int m = 0; m < 2; ++m)
#pragma unroll
        for (int c = 0; c < 4; ++c) acc[m][c] = {0.f, 0.f, 0.f, 0.f};

    int rowA0 = r0 + l15;
    int rowA1 = r0 + 16 + l15;
    int cr0 = rowA0 < M ? rowA0 : M - 1;
    int cr1 = rowA1 < M ? rowA1 : M - 1;
    const float* pA0 = x + (size_t)cr0 * K + lhi * 8;
    const float* pA1 = x + (size_t)cr1 * K + lhi * 8;
    const bf16x8* Wv = (const bf16x8*)Wlds;

    for (int kk = 0; kk < K; kk += 32) {
        float4 a0l = *(const float4*)(pA0 + kk);
        float4 a0h = *(const float4*)(pA0 + kk + 4);
        float4 a1l = *(const float4*)(pA1 + kk);
        float4 a1h = *(const float4*)(pA1 + kk + 4);
        bf16x8 af0, af1;
        af0[0] = (__bf16)a0l.x; af0[1] = (__bf16)a0l.y;
        af0[2] = (__bf16)a0l.z; af0[3] = (__bf16)a0l.w;
        af0[4] = (__bf16)a0h.x; af0[5] = (__bf16)a0h.y;
        af0[6] = (__bf16)a0h.z; af0[7] = (__bf16)a0h.w;
        af1[0] = (__bf16)a1l.x; af1[1] = (__bf16)a1l.y;
        af1[2] = (__bf16)a1l.z; af1[3] = (__bf16)a1l.w;
        af1[4] = (__bf16)a1h.x; af1[5] = (__bf16)a1h.y;
        af1[6] = (__bf16)a1h.z; af1[7] = (__bf16)a1h.w;
        const int kblk = (kk >> 3) + lhi;
#pragma unroll
        for (int c = 0; c < 4; ++c) {
            bf16x8 bf = Wv[kblk * 64 + c * 16 + l15];
            acc[0][c] = __builtin_amdgcn_mfma_f32_16x16x32_bf16(af0, bf, acc[0][c], 0, 0, 0);
            acc[1][c] = __builtin_amdgcn_mfma_f32_16x16x32_bf16(af1, bf, acc[1][c], 0, 0, 0);
        }
    }

#pragma unroll
    for (int m = 0; m < 2; ++m) {
        int rbase = r0 + m * 16 + lhi * 4;
#pragma unroll
        for (int c = 0; c < 4; ++c) {
            int col = c * 16 + l15;
#pragma unroll
            for (int r = 0; r < 4; ++r) {
                int row = rbase + r;
                if (row < M) h[(size_t)row * 64 + col] = acc[m][c][r];
            }
        }
    }
}

// ---------------- counting sort machinery ----------------
__global__ void zero2_kernel(int* __restrict__ a, int na, int* __restrict__ b, int nb) {
    int i = blockIdx.x * blockDim.x + threadIdx.x;
    if (i < na) a[i] = 0;
    else if (i < na + nb) b[i - na] = 0;
}

__global__ void hist_kernel(const int* __restrict__ ei, int* __restrict__ cnt, int E) {
    int i = blockIdx.x * blockDim.x + threadIdx.x;
    if (i < E) atomicAdd(&cnt[ei[E + i]], 1);
}

__global__ void __launch_bounds__(1024)
exscan2_kernel(const int* __restrict__ cnt1, int* __restrict__ start1, int* __restrict__ cur1, int n1,
               const int* __restrict__ cnt2, int* __restrict__ start2, int* __restrict__ cur2, int n2) {
    const int* cnt; int* start; int* cur; int n;
    if (blockIdx.x == 0) { cnt = cnt1; start = start1; cur = cur1; n = n1; }
    else                 { cnt = cnt2; start = start2; cur = cur2; n = n2; }

    __shared__ int wsum[16];
    __shared__ int s_running;
    if (threadIdx.x == 0) s_running = 0;
    __syncthreads();

    int lane = threadIdx.x & 63;
    int wid  = threadIdx.x >> 6;

    for (int base = 0; base < n; base += 4096) {
        int e0 = base + threadIdx.x * 4;
        int4 v = (e0 < n) ? *reinterpret_cast<const int4*>(&cnt[e0]) : make_int4(0, 0, 0, 0);
        int s0 = v.x;
        int s1 = s0 + v.y;
        int s2 = s1 + v.z;
        int s3 = s2 + v.w;
        int tsum = s3;
        int incl = tsum;
#pragma unroll
        for (int off = 1; off < 64; off <<= 1) {
            int t = __shfl_up(incl, off);
            if (lane >= off) incl += t;
        }
        if (lane == 63) wsum[wid] = incl;
        __syncthreads();
        int wave_excl = 0;
        for (int w = 0; w < wid; ++w) wave_excl += wsum[w];
        int excl_t = wave_excl + (incl - tsum) + s_running;
        if (e0 < n) {
            int4 o = make_int4(excl_t, excl_t + s0, excl_t + s1, excl_t + s2);
            *reinterpret_cast<int4*>(&start[e0]) = o;
            *reinterpret_cast<int4*>(&cur[e0])   = o;
        }
        __syncthreads();
        if (threadIdx.x == 1023) s_running += wave_excl + incl;
        __syncthreads();
    }
    if (threadIdx.x == 0) start[n] = s_running;
}

__global__ void place_kernel(const int* __restrict__ ei, int* __restrict__ cursor,
                             int* __restrict__ sorted_src, int E) {
    int i = blockIdx.x * blockDim.x + threadIdx.x;
    if (i < E) {
        int dst = ei[E + i];
        int pos = atomicAdd(&cursor[dst], 1);
        sorted_src[pos] = ei[i];
    }
}

// ---------------- segmented gather-reduce ----------------
__global__ void gather_reduce_kernel(const int* __restrict__ start,
                                     const int* __restrict__ sorted_src,
                                     const float* __restrict__ h,
                                     const float* __restrict__ bias,
                                     float* __restrict__ out, int N) {
    int wave = (blockIdx.x * blockDim.x + threadIdx.x) >> 6;
    int lane = threadIdx.x & 63;
    if (wave >= N) return;
    int s = start[wave];
    int e = start[wave + 1];
    float acc0 = bias[lane], acc1 = 0.f, acc2 = 0.f, acc3 = 0.f;
    for (int b = s; b < e; b += 64) {
        int m = e - b;
        if (m > 64) m = 64;
        int id = (lane < m) ? sorted_src[b + lane] : 0;
        int j = 0;
        for (; j + 4 <= m; j += 4) {
            int s0 = __shfl(id, j);
            int s1 = __shfl(id, j + 1);
            int s2 = __shfl(id, j + 2);
            int s3 = __shfl(id, j + 3);
            float v0 = h[(size_t)s0 * NHID + lane];
            float v1 = h[(size_t)s1 * NHID + lane];
            float v2 = h[(size_t)s2 * NHID + lane];
            float v3 = h[(size_t)s3 * NHID + lane];
            acc0 += v0; acc1 += v1; acc2 += v2; acc3 += v3;
        }
        for (; j < m; ++j) {
            int sn = __shfl(id, j);
            acc0 += h[(size_t)sn * NHID + lane];
        }
    }
    out[(size_t)wave * NHID + lane] = (acc0 + acc1) + (acc2 + acc3);
}

extern "C" void kernel_launch(void* const* d_in, const int* in_sizes, int n_in,
                              void* d_out, int out_size, void* d_ws, size_t ws_size,
                              hipStream_t stream) {
    const float* drug_x = (const float*)d_in[0];
    const float* dis_x  = (const float*)d_in[1];
    const float* W1     = (const float*)d_in[2];
    const float* b1     = (const float*)d_in[3];
    const float* W2     = (const float*)d_in[4];
    const float* b2     = (const float*)d_in[5];
    const int*   ei1    = (const int*)d_in[6];
    const int*   ei2    = (const int*)d_in[7];
    float* out = (float*)d_out;

    // workspace layout (16B-aligned chunks)
    char* p = (char*)d_ws;
    float* h1 = (float*)p;            p += (size_t)N_DRUG * NHID * 4;
    float* h2 = (float*)p;            p += (size_t)N_DIS  * NHID * 4;
    int* cnt1   = (int*)p;            p += (size_t)N_DRUG * 4;
    int* start1 = (int*)p;            p += ((size_t)N_DRUG + 4) * 4;
    int* cur1   = (int*)p;            p += (size_t)N_DRUG * 4;
    int* cnt2   = (int*)p;            p += (size_t)N_DIS * 4;
    int* start2 = (int*)p;            p += ((size_t)N_DIS + 4) * 4;
    int* cur2   = (int*)p;            p += (size_t)N_DIS * 4;
    int* srt1   = (int*)p;            p += (size_t)E_DRUG * 4;
    int* srt2   = (int*)p;            /* p += E_DIS*4 */

    // Wp1/Wp2 reuse cnt1's region (dead after exscan; prepack launches after it).
    __bf16* Wp1 = (__bf16*)cnt1;                       // 32 KB
    __bf16* Wp2 = Wp1 + (size_t)F_DRUG * NHID;         // 16 KB  (cnt1 region = 200 KB)

    // 1) zero histograms
    {
        int total = N_DRUG + N_DIS;
        zero2_kernel<<<(total + 255) / 256, 256, 0, stream>>>(cnt1, N_DRUG, cnt2, N_DIS);
    }
    // 2) histograms of dst
    hist_kernel<<<(E_DRUG + 255) / 256, 256, 0, stream>>>(ei1, cnt1, E_DRUG);
    hist_kernel<<<(E_DIS  + 255) / 256, 256, 0, stream>>>(ei2, cnt2, E_DIS);
    // 3) exclusive scans
    exscan2_kernel<<<2, 1024, 0, stream>>>(cnt1, start1, cur1, N_DRUG,
                                           cnt2, start2, cur2, N_DIS);
    // 4) prepack W (cnt1 now dead -> safe to overwrite)
    {
        int n1 = F_DRUG * NHID, n2 = F_DIS * NHID;
        prepack_kernel<<<(n1 + n2 + 255) / 256, 256, 0, stream>>>(W1, Wp1, n1, W2, Wp2, n2);
    }
    // 5) place src ids in dst-sorted order
    place_kernel<<<(E_DRUG + 255) / 256, 256, 0, stream>>>(ei1, cur1, srt1, E_DRUG);
    place_kernel<<<(E_DIS  + 255) / 256, 256, 0, stream>>>(ei2, cur2, srt2, E_DIS);
    // 6) MFMA GEMMs
    mfma_gemm_kernel<F_DRUG><<<(N_DRUG + 127) / 128, 256, 0, stream>>>(drug_x, Wp1, h1, N_DRUG);
    mfma_gemm_kernel<F_DIS ><<<(N_DIS  + 127) / 128, 256, 0, stream>>>(dis_x,  Wp2, h2, N_DIS);
    // 7) segmented gather-reduce (+bias)
    gather_reduce_kernel<<<N_DRUG / 4, 256, 0, stream>>>(start1, srt1, h1, b1, out, N_DRUG);
    gather_reduce_kernel<<<N_DIS / 4, 256, 0, stream>>>(start2, srt2, h2, b2,
                                                        out + (size_t)N_DRUG * NHID, N_DIS);
}